// Round 1
// baseline (1805.724 us; speedup 1.0000x reference)
//
#include <hip/hip_runtime.h>
#include <math.h>

#define BKS 60      // B*K sequences
#define TL  1000    // T
#define NF  128     // N features
#define SD  12      // state dim S
#define RD  8       // dt rank
#define NCH 25      // scan chunks
#define CLEN 40     // chunk length (NCH*CLEN == TL)
#define NTOK (BKS*TL)

__device__ __forceinline__ float siluf(float x){ return x / (1.f + __expf(-x)); }
__device__ __forceinline__ float softplusf(float x){
  if (x > 20.f) return x;
  float e = __expf(x);
  return (x < -20.f) ? e : __logf(1.f + e);
}

// ---- K0: x (B,N,T,K) -> seq (B*K, T, N), one block per (b,t)
__global__ __launch_bounds__(256) void k_ingest(const float* __restrict__ x, float* __restrict__ seq){
  const int b = blockIdx.x / TL, t = blockIdx.x % TL;
  __shared__ float tile[30*NF];
  for (int e = threadIdx.x; e < 30*NF; e += 256){
    int n = e / 30, k = e - n*30;
    tile[k*NF + n] = x[((size_t)(b*NF + n)*TL + t)*30 + k];
  }
  __syncthreads();
  const size_t base = ((size_t)b*30)*TL*NF + (size_t)t*NF;
  for (int e = threadIdx.x; e < 30*NF; e += 256){
    int k = e >> 7, n = e & 127;
    seq[base + (size_t)k*TL*NF + n] = tile[e];
  }
}

// ---- K1: LayerNorm + in_proj (2N x N), 16 tokens per block of 256
__global__ __launch_bounds__(256) void k_ln_inproj(
    const float* __restrict__ seq, const float* __restrict__ lnw, const float* __restrict__ lnb,
    const float* __restrict__ iw, const float* __restrict__ ib,
    float* __restrict__ xcr, float* __restrict__ zb){
  __shared__ float xn[16*NF];
  const int tok0 = blockIdx.x * 16;
  {
    const int j = threadIdx.x >> 4;     // token in block
    const int l16 = threadIdx.x & 15;
    const float* sp = seq + ((size_t)(tok0 + j))*NF;
    float v[8]; float s = 0.f, s2 = 0.f;
    #pragma unroll
    for (int i = 0; i < 8; ++i){ float f = sp[l16 + 16*i]; v[i] = f; s += f; s2 += f*f; }
    #pragma unroll
    for (int m = 1; m < 16; m <<= 1){ s += __shfl_xor(s, m, 64); s2 += __shfl_xor(s2, m, 64); }
    const float mean = s * (1.f/128.f);
    const float rstd = rsqrtf(s2*(1.f/128.f) - mean*mean + 1e-5f);
    #pragma unroll
    for (int i = 0; i < 8; ++i){
      int n = l16 + 16*i;
      xn[j*NF + n] = (v[i]-mean)*rstd*lnw[n] + lnb[n];
    }
  }
  __syncthreads();
  const int o = threadIdx.x;            // output column 0..255
  const float4* wr = (const float4*)(iw + (size_t)o*NF);
  float acc[16];
  #pragma unroll
  for (int i = 0; i < 16; ++i) acc[i] = 0.f;
  for (int k4 = 0; k4 < 32; ++k4){
    float4 w4 = wr[k4];
    #pragma unroll
    for (int i = 0; i < 16; ++i){
      float4 x4 = *((const float4*)&xn[i*NF + k4*4]);   // LDS broadcast
      acc[i] = fmaf(w4.x, x4.x, fmaf(w4.y, x4.y, fmaf(w4.z, x4.z, fmaf(w4.w, x4.w, acc[i]))));
    }
  }
  const float bo = ib[o];
  float* dst = (o < NF) ? (xcr + (size_t)tok0*NF + o) : (zb + (size_t)tok0*NF + (o - NF));
  #pragma unroll
  for (int i = 0; i < 16; ++i) dst[(size_t)i*NF] = acc[i] + bo;
}

// ---- K2: causal depthwise conv(DC=4)+silu, then x-proj (32xN) and dt=softplus(.), B, C
__global__ __launch_bounds__(128) void k_conv_dt(
    const float* __restrict__ xcr,
    const float* __restrict__ cw, const float* __restrict__ cb,
    const float* __restrict__ xw, const float* __restrict__ dw, const float* __restrict__ db,
    float* __restrict__ xcc, float* __restrict__ dtb,
    float* __restrict__ Bmb, float* __restrict__ Cmb){
  const int blk = blockIdx.x;
  const int sq = blk / TL, t = blk - sq*TL;
  const int n = threadIdx.x;
  float a = cb[n];
  #pragma unroll
  for (int k = 0; k < 4; ++k){
    int tt = t - 3 + k;
    float xv = (tt >= 0) ? xcr[((size_t)sq*TL + tt)*NF + n] : 0.f;
    a = fmaf(xv, cw[n*4 + k], a);
  }
  float xc = siluf(a);
  __shared__ float sx[NF];
  __shared__ float sdbc[32];
  sx[n] = xc;
  xcc[(size_t)blk*NF + n] = xc;
  __syncthreads();
  {
    const int o = n >> 2, part = n & 3;   // 4 lanes per output, 32 outputs
    const float4* wr = (const float4*)(xw + (size_t)o*NF + part*32);
    const float4* xr = (const float4*)(sx + part*32);
    float sum = 0.f;
    #pragma unroll
    for (int q = 0; q < 8; ++q){
      float4 w4 = wr[q], x4 = xr[q];
      sum = fmaf(w4.x,x4.x, fmaf(w4.y,x4.y, fmaf(w4.z,x4.z, fmaf(w4.w,x4.w, sum))));
    }
    sum += __shfl_xor(sum, 1, 64);
    sum += __shfl_xor(sum, 2, 64);
    if (part == 0) sdbc[o] = sum;
  }
  __syncthreads();
  float accd = db[n];
  #pragma unroll
  for (int r = 0; r < 8; ++r) accd = fmaf(sdbc[r], dw[n*8 + r], accd);
  dtb[(size_t)blk*NF + n] = softplusf(accd);
  if (n < SD)            Bmb[(size_t)blk*SD + n]        = sdbc[8 + n];
  else if (n < 2*SD)     Cmb[(size_t)blk*SD + (n - SD)] = sdbc[8 + n];
}

// ---- K3a: scan pass 1 — per-chunk local recurrence from h=0; record prod(dA) and local h_final
__global__ __launch_bounds__(128) void k_scan_pass1(
    const float* __restrict__ dtb, const float* __restrict__ xcc,
    const float* __restrict__ Bmb, const float* __restrict__ alog,
    float* __restrict__ ap, float* __restrict__ hfb){
  const int bid = blockIdx.x;
  const int sq = bid / NCH, c = bid - sq*NCH;
  const int n = threadIdx.x;
  const float4* A4 = (const float4*)(alog + (size_t)n*SD);
  float4 Aa = A4[0], Ab = A4[1], Ac = A4[2];
  float Av[SD] = {Aa.x,Aa.y,Aa.z,Aa.w, Ab.x,Ab.y,Ab.z,Ab.w, Ac.x,Ac.y,Ac.z,Ac.w};
  #pragma unroll
  for (int s = 0; s < SD; ++s) Av[s] = -__expf(Av[s]);
  float h[SD], apv[SD];
  #pragma unroll
  for (int s = 0; s < SD; ++s){ h[s] = 0.f; apv[s] = 1.f; }
  const size_t tok0 = (size_t)sq*TL + c*CLEN;
  for (int tt = 0; tt < CLEN; ++tt){
    const size_t tok = tok0 + tt;
    float dtv = dtb[tok*NF + n];
    float dx  = dtv * xcc[tok*NF + n];
    const float4* B4 = (const float4*)(Bmb + tok*SD);   // broadcast across lanes
    float4 Ba = B4[0], Bb = B4[1], Bc = B4[2];
    float Bv[SD] = {Ba.x,Ba.y,Ba.z,Ba.w, Bb.x,Bb.y,Bb.z,Bb.w, Bc.x,Bc.y,Bc.z,Bc.w};
    #pragma unroll
    for (int s = 0; s < SD; ++s){
      float dA = __expf(dtv*Av[s]);
      h[s] = fmaf(dA, h[s], dx*Bv[s]);
      apv[s] *= dA;
    }
  }
  const size_t base = (size_t)bid*SD*NF + n;
  #pragma unroll
  for (int s = 0; s < SD; ++s){ ap[base + s*NF] = apv[s]; hfb[base + s*NF] = h[s]; }
}

// ---- K3b: sequential combine across chunks -> initial h per chunk
__global__ __launch_bounds__(128) void k_scan_combine(
    const float* __restrict__ ap, const float* __restrict__ hfb, float* __restrict__ hinit){
  const int sq = blockIdx.x;
  const int n = threadIdx.x;
  float h[SD];
  #pragma unroll
  for (int s = 0; s < SD; ++s) h[s] = 0.f;
  for (int c = 0; c < NCH; ++c){
    const size_t base = ((size_t)sq*NCH + c)*SD*NF + n;
    #pragma unroll
    for (int s = 0; s < SD; ++s){
      hinit[base + s*NF] = h[s];
      h[s] = fmaf(ap[base + s*NF], h[s], hfb[base + s*NF]);
    }
  }
}

// ---- K3c: scan pass 2 — replay with correct h_init, emit y
__global__ __launch_bounds__(128) void k_scan_pass2(
    const float* __restrict__ dtb, const float* __restrict__ xcc,
    const float* __restrict__ Bmb, const float* __restrict__ Cmb,
    const float* __restrict__ alog, const float* __restrict__ hinit,
    float* __restrict__ yb){
  const int bid = blockIdx.x;
  const int sq = bid / NCH, c = bid - sq*NCH;
  const int n = threadIdx.x;
  const float4* A4 = (const float4*)(alog + (size_t)n*SD);
  float4 Aa = A4[0], Ab = A4[1], Ac = A4[2];
  float Av[SD] = {Aa.x,Aa.y,Aa.z,Aa.w, Ab.x,Ab.y,Ab.z,Ab.w, Ac.x,Ac.y,Ac.z,Ac.w};
  #pragma unroll
  for (int s = 0; s < SD; ++s) Av[s] = -__expf(Av[s]);
  float h[SD];
  const size_t hbase = (size_t)bid*SD*NF + n;
  #pragma unroll
  for (int s = 0; s < SD; ++s) h[s] = hinit[hbase + s*NF];
  const size_t tok0 = (size_t)sq*TL + c*CLEN;
  for (int tt = 0; tt < CLEN; ++tt){
    const size_t tok = tok0 + tt;
    float dtv = dtb[tok*NF + n];
    float dx  = dtv * xcc[tok*NF + n];
    const float4* B4 = (const float4*)(Bmb + tok*SD);
    const float4* C4 = (const float4*)(Cmb + tok*SD);
    float4 Ba=B4[0], Bb=B4[1], Bc=B4[2];
    float4 Ca=C4[0], Cb=C4[1], Cc=C4[2];
    float Bv[SD] = {Ba.x,Ba.y,Ba.z,Ba.w, Bb.x,Bb.y,Bb.z,Bb.w, Bc.x,Bc.y,Bc.z,Bc.w};
    float Cv[SD] = {Ca.x,Ca.y,Ca.z,Ca.w, Cb.x,Cb.y,Cb.z,Cb.w, Cc.x,Cc.y,Cc.z,Cc.w};
    float yv = 0.f;
    #pragma unroll
    for (int s = 0; s < SD; ++s){
      float dA = __expf(dtv*Av[s]);
      h[s] = fmaf(dA, h[s], dx*Bv[s]);
      yv = fmaf(h[s], Cv[s], yv);
    }
    yb[tok*NF + n] = yv;
  }
}

// ---- K4: y2 = (y + Dv*xc) * silu(z); seq += y2 @ out_w^T + out_b   (16 tokens/block)
__global__ __launch_bounds__(256) void k_gate_out(
    const float* __restrict__ yb, const float* __restrict__ xcc, const float* __restrict__ zb,
    const float* __restrict__ Dv, const float* __restrict__ ow, const float* __restrict__ ob,
    float* __restrict__ seq){
  __shared__ float sy[16*NF];
  const int tok0 = blockIdx.x * 16;
  for (int e = threadIdx.x; e < 16*NF; e += 256){
    int n = e & 127;
    size_t idx = (size_t)tok0*NF + e;
    float yv = fmaf(Dv[n], xcc[idx], yb[idx]);
    sy[e] = yv * siluf(zb[idx]);
  }
  __syncthreads();
  const int n = threadIdx.x & 127, jg = threadIdx.x >> 7;
  const float4* wr = (const float4*)(ow + (size_t)n*NF);
  float acc[8];
  #pragma unroll
  for (int i = 0; i < 8; ++i) acc[i] = 0.f;
  for (int k4 = 0; k4 < 32; ++k4){
    float4 w4 = wr[k4];
    #pragma unroll
    for (int i = 0; i < 8; ++i){
      float4 x4 = *((const float4*)&sy[(jg*8 + i)*NF + k4*4]);
      acc[i] = fmaf(w4.x,x4.x, fmaf(w4.y,x4.y, fmaf(w4.z,x4.z, fmaf(w4.w,x4.w, acc[i]))));
    }
  }
  const float bo = ob[n];
  #pragma unroll
  for (int i = 0; i < 8; ++i){
    size_t idx = ((size_t)(tok0 + jg*8 + i))*NF + n;
    seq[idx] += acc[i] + bo;
  }
}

// ---- K5: cross block + final LN + transpose to (B,N,T,K); one block per (b,t)
__global__ __launch_bounds__(256) void k_cross_final(
    const float* __restrict__ seq,
    const float* __restrict__ cbw, const float* __restrict__ cbb,
    const float* __restrict__ clnw, const float* __restrict__ clnb,
    const float* __restrict__ flnw, const float* __restrict__ flnb,
    float* __restrict__ out){
  const int b = blockIdx.x / TL, t = blockIdx.x % TL;
  __shared__ float Sm[30*NF];
  __shared__ float Cx[30*NF];
  __shared__ float mu[30], rsd[30];
  for (int e = threadIdx.x; e < 30*NF; e += 256){
    int k = e >> 7, n = e & 127;
    Sm[e] = seq[((size_t)(b*30 + k)*TL + t)*NF + n];
  }
  __syncthreads();
  for (int e = threadIdx.x; e < 30*NF; e += 256){
    int k = e >> 7, n = e & 127;
    const float4* wr = (const float4*)(cbw + (size_t)n*NF);
    const float4* xr = (const float4*)(&Sm[k*NF]);
    float acc2 = 0.f;
    for (int q = 0; q < 32; ++q){
      float4 w4 = wr[q], x4 = xr[q];
      acc2 = fmaf(w4.x,x4.x, fmaf(w4.y,x4.y, fmaf(w4.z,x4.z, fmaf(w4.w,x4.w, acc2))));
    }
    Cx[e] = acc2 + cbb[n];
  }
  __syncthreads();
  if (threadIdx.x < 30){
    int k = threadIdx.x;
    float s = 0.f, s2 = 0.f;
    for (int q = 0; q < NF; ++q){ float v = Cx[k*NF + q]; s += v; s2 += v*v; }
    float m = s * (1.f/128.f);
    mu[k] = m; rsd[k] = rsqrtf(s2*(1.f/128.f) - m*m + 1e-5f);
  }
  __syncthreads();
  for (int e = threadIdx.x; e < 30*NF; e += 256){
    int k = e >> 7, n = e & 127;
    float cn = (Cx[e] - mu[k])*rsd[k]*clnw[n] + clnb[n];
    float g = 0.5f*cn*(1.f + erff(cn*0.70710678118f));   // exact gelu
    Cx[e] = Sm[e] + g;
  }
  __syncthreads();
  if (threadIdx.x < 30){
    int k = threadIdx.x;
    float s = 0.f, s2 = 0.f;
    for (int q = 0; q < NF; ++q){ float v = Cx[k*NF + q]; s += v; s2 += v*v; }
    float m = s * (1.f/128.f);
    mu[k] = m; rsd[k] = rsqrtf(s2*(1.f/128.f) - m*m + 1e-5f);
  }
  __syncthreads();
  for (int e = threadIdx.x; e < 30*NF; e += 256){
    int n = e / 30, k = e - n*30;   // k fastest for coalesced write
    float v = (Cx[k*NF + n] - mu[k])*rsd[k]*flnw[n] + flnb[n];
    out[((size_t)(b*NF + n)*TL + t)*30 + k] = v;
  }
}

extern "C" void kernel_launch(void* const* d_in, const int* in_sizes, int n_in,
                              void* d_out, int out_size, void* d_ws, size_t ws_size,
                              hipStream_t stream){
  const float* x       = (const float*)d_in[0];
  const float* ln_w    = (const float*)d_in[1];
  const float* ln_b    = (const float*)d_in[2];
  const float* in_w    = (const float*)d_in[3];
  const float* in_b    = (const float*)d_in[4];
  const float* conv_w  = (const float*)d_in[5];
  const float* conv_b  = (const float*)d_in[6];
  const float* xp_w    = (const float*)d_in[7];
  const float* dtp_w   = (const float*)d_in[8];
  const float* dtp_b   = (const float*)d_in[9];
  const float* A_log   = (const float*)d_in[10];
  const float* Dv      = (const float*)d_in[11];
  const float* out_w   = (const float*)d_in[12];
  const float* out_b   = (const float*)d_in[13];
  const float* cb_w    = (const float*)d_in[14];
  const float* cb_b    = (const float*)d_in[15];
  const float* cb_ln_w = (const float*)d_in[16];
  const float* cb_ln_b = (const float*)d_in[17];
  const float* fin_ln_w= (const float*)d_in[18];
  const float* fin_ln_b= (const float*)d_in[19];
  float* out = (float*)d_out;

  const size_t SEQSZ = (size_t)BKS*TL*NF;    // 7,680,000 floats
  const size_t CHSZ  = (size_t)BKS*NF*NCH*SD; // 2,304,000 floats
  float* ws  = (float*)d_ws;
  float* seq = ws;
  float* xcr = ws + SEQSZ;        // dead after k_conv_dt -> reused for scan scratch
  float* zb  = ws + 2*SEQSZ;
  float* xcc = ws + 3*SEQSZ;
  float* dtb = ws + 4*SEQSZ;
  float* yb  = ws + 5*SEQSZ;
  float* Bmb = ws + 6*SEQSZ;
  float* Cmb = Bmb + (size_t)BKS*TL*SD;
  float* ap    = xcr;             // aliases xcr (3*CHSZ = 6.912M <= 7.68M floats)
  float* hfb   = xcr + CHSZ;
  float* hinit = xcr + 2*CHSZ;
  if (ws_size < (6*SEQSZ + 2*(size_t)BKS*TL*SD)*sizeof(float)) return; // need ~190 MB

  k_ingest<<<2*TL, 256, 0, stream>>>(x, seq);
  for (int l = 0; l < 4; ++l){
    k_ln_inproj<<<NTOK/16, 256, 0, stream>>>(seq, ln_w + l*NF, ln_b + l*NF,
        in_w + (size_t)l*2*NF*NF, in_b + l*2*NF, xcr, zb);
    k_conv_dt<<<NTOK, 128, 0, stream>>>(xcr, conv_w + (size_t)l*NF*4, conv_b + l*NF,
        xp_w + (size_t)l*32*NF, dtp_w + (size_t)l*NF*RD, dtp_b + l*NF, xcc, dtb, Bmb, Cmb);
    k_scan_pass1<<<BKS*NCH, NF, 0, stream>>>(dtb, xcc, Bmb, A_log + (size_t)l*NF*SD, ap, hfb);
    k_scan_combine<<<BKS, NF, 0, stream>>>(ap, hfb, hinit);
    k_scan_pass2<<<BKS*NCH, NF, 0, stream>>>(dtb, xcc, Bmb, Cmb, A_log + (size_t)l*NF*SD, hinit, yb);
    k_gate_out<<<NTOK/16, 256, 0, stream>>>(yb, xcc, zb, Dv + l*NF,
        out_w + (size_t)l*NF*NF, out_b + l*NF, seq);
  }
  k_cross_final<<<2*TL, 256, 0, stream>>>(seq, cb_w, cb_b, cb_ln_w, cb_ln_b, fin_ln_w, fin_ln_b, out);
}

// Round 2
// 1433.224 us; speedup vs baseline: 1.2599x; 1.2599x over previous
//
#include <hip/hip_runtime.h>
#include <math.h>

#define BKS 60      // B*K sequences
#define TL  1000    // T
#define NF  128     // N features
#define SD  12      // state dim S
#define RD  8       // dt rank
#define NCH 25      // scan chunks
#define CLEN 40     // chunk length (NCH*CLEN == TL)
#define NTOK (BKS*TL)

__device__ __forceinline__ float siluf(float x){ return x / (1.f + __expf(-x)); }
__device__ __forceinline__ float softplusf(float x){
  if (x > 20.f) return x;
  float e = __expf(x);
  return (x < -20.f) ? e : __logf(1.f + e);
}

// ---- K0: x (B,N,T,K) -> seq (B*K, T, N), one block per (b,t)
__global__ __launch_bounds__(256) void k_ingest(const float* __restrict__ x, float* __restrict__ seq){
  const int b = blockIdx.x / TL, t = blockIdx.x % TL;
  __shared__ float tile[30*NF];
  for (int e = threadIdx.x; e < 30*NF; e += 256){
    int n = e / 30, k = e - n*30;
    tile[k*NF + n] = x[((size_t)(b*NF + n)*TL + t)*30 + k];
  }
  __syncthreads();
  const size_t base = ((size_t)b*30)*TL*NF + (size_t)t*NF;
  for (int e = threadIdx.x; e < 30*NF; e += 256){
    int k = e >> 7, n = e & 127;
    seq[base + (size_t)k*TL*NF + n] = tile[e];
  }
}

// ---- K1: LayerNorm + in_proj (2N x N), 16 tokens per block of 256
__global__ __launch_bounds__(256) void k_ln_inproj(
    const float* __restrict__ seq, const float* __restrict__ lnw, const float* __restrict__ lnb,
    const float* __restrict__ iw, const float* __restrict__ ib,
    float* __restrict__ xcr, float* __restrict__ zb){
  __shared__ float xn[16*NF];
  const int tok0 = blockIdx.x * 16;
  {
    const int j = threadIdx.x >> 4;     // token in block
    const int l16 = threadIdx.x & 15;
    const float* sp = seq + ((size_t)(tok0 + j))*NF;
    float v[8]; float s = 0.f, s2 = 0.f;
    #pragma unroll
    for (int i = 0; i < 8; ++i){ float f = sp[l16 + 16*i]; v[i] = f; s += f; s2 += f*f; }
    #pragma unroll
    for (int m = 1; m < 16; m <<= 1){ s += __shfl_xor(s, m, 64); s2 += __shfl_xor(s2, m, 64); }
    const float mean = s * (1.f/128.f);
    const float rstd = rsqrtf(s2*(1.f/128.f) - mean*mean + 1e-5f);
    #pragma unroll
    for (int i = 0; i < 8; ++i){
      int n = l16 + 16*i;
      xn[j*NF + n] = (v[i]-mean)*rstd*lnw[n] + lnb[n];
    }
  }
  __syncthreads();
  const int o = threadIdx.x;            // output column 0..255
  const float4* wr = (const float4*)(iw + (size_t)o*NF);
  float acc[16];
  #pragma unroll
  for (int i = 0; i < 16; ++i) acc[i] = 0.f;
  for (int k4 = 0; k4 < 32; ++k4){
    float4 w4 = wr[k4];
    #pragma unroll
    for (int i = 0; i < 16; ++i){
      float4 x4 = *((const float4*)&xn[i*NF + k4*4]);   // LDS broadcast
      acc[i] = fmaf(w4.x, x4.x, fmaf(w4.y, x4.y, fmaf(w4.z, x4.z, fmaf(w4.w, x4.w, acc[i]))));
    }
  }
  const float bo = ib[o];
  float* dst = (o < NF) ? (xcr + (size_t)tok0*NF + o) : (zb + (size_t)tok0*NF + (o - NF));
  #pragma unroll
  for (int i = 0; i < 16; ++i) dst[(size_t)i*NF] = acc[i] + bo;
}

// ---- K2 (rewritten): 40 tokens/block. conv(DC=4)+silu -> x-proj(32xN) -> dt/B/C.
// 1500 blocks x 256 threads. LDS: input tile w/ halo + conv result + dbc.
__global__ __launch_bounds__(256) void k_conv_dt(
    const float* __restrict__ xcr,
    const float* __restrict__ cw, const float* __restrict__ cb,
    const float* __restrict__ xw, const float* __restrict__ dw, const float* __restrict__ db,
    float* __restrict__ xcc, float* __restrict__ dtb,
    float* __restrict__ Bmb, float* __restrict__ Cmb){
  __shared__ float sxr[(CLEN+3)*NF];   // rows 0..42 = tokens t0-3 .. t0+39
  __shared__ float sxc[CLEN*NF];       // conv+silu result
  __shared__ float sdbc[CLEN*32];      // x-proj output (dt-rank 8, B 12, C 12)
  const int sq = blockIdx.x / NCH, cblk = blockIdx.x - sq*NCH;
  const int t0 = cblk*CLEN;
  const int tid = threadIdx.x;

  // stage input tile (coalesced; zero-pad before sequence start)
  for (int e = tid; e < (CLEN+3)*NF; e += 256){
    int r = e >> 7, n = e & 127;
    int t = t0 - 3 + r;
    sxr[e] = (t >= 0) ? xcr[((size_t)sq*TL + t)*NF + n] : 0.f;
  }
  __syncthreads();

  // conv + silu (each thread 20 elements)
  #pragma unroll
  for (int i = 0; i < (CLEN*NF)/256; ++i){
    int e = tid + i*256;
    int r = e >> 7, n = e & 127;
    float a = cb[n];
    #pragma unroll
    for (int k = 0; k < 4; ++k)
      a = fmaf(sxr[(r+k)*NF + n], cw[n*4 + k], a);
    float v = siluf(a);
    sxc[e] = v;
    xcc[((size_t)sq*TL + t0)*NF + e] = v;   // coalesced store
  }
  __syncthreads();

  // x-proj: dbc[t][o] = dot(xc[t], xw[o]);  o = tid&31, token group jg = tid>>5 (5 tokens each)
  {
    const int o = tid & 31, jg = tid >> 5;
    const float4* wr = (const float4*)(xw + (size_t)o*NF);
    float acc[5];
    #pragma unroll
    for (int j = 0; j < 5; ++j) acc[j] = 0.f;
    for (int k4 = 0; k4 < 32; ++k4){
      float4 w4 = wr[k4];
      #pragma unroll
      for (int j = 0; j < 5; ++j){
        float4 x4 = *((const float4*)&sxc[(jg*5 + j)*NF + k4*4]);  // wave-broadcast
        acc[j] = fmaf(w4.x,x4.x, fmaf(w4.y,x4.y, fmaf(w4.z,x4.z, fmaf(w4.w,x4.w, acc[j]))));
      }
    }
    #pragma unroll
    for (int j = 0; j < 5; ++j) sdbc[(jg*5 + j)*32 + o] = acc[j];
  }
  __syncthreads();

  // dt-projection + softplus (each thread 20 (token,n) pairs)
  #pragma unroll
  for (int i = 0; i < (CLEN*NF)/256; ++i){
    int e = tid + i*256;
    int r = e >> 7, n = e & 127;
    float acc = db[n];
    #pragma unroll
    for (int q = 0; q < 8; ++q)
      acc = fmaf(sdbc[r*32 + q], dw[n*8 + q], acc);
    dtb[((size_t)sq*TL + t0)*NF + e] = softplusf(acc);
  }
  // B / C extraction
  for (int e = tid; e < CLEN*2*SD; e += 256){
    int r = e / (2*SD), c = e - r*2*SD;
    float v = sdbc[r*32 + 8 + c];
    size_t tok = (size_t)sq*TL + t0 + r;
    if (c < SD) Bmb[tok*SD + c] = v;
    else        Cmb[tok*SD + (c - SD)] = v;
  }
}

// ---- K3a: scan pass 1 — per-chunk local recurrence from h=0; record prod(dA) and local h_final
__global__ __launch_bounds__(128) void k_scan_pass1(
    const float* __restrict__ dtb, const float* __restrict__ xcc,
    const float* __restrict__ Bmb, const float* __restrict__ alog,
    float* __restrict__ ap, float* __restrict__ hfb){
  const int bid = blockIdx.x;
  const int sq = bid / NCH, c = bid - sq*NCH;
  const int n = threadIdx.x;
  const float4* A4 = (const float4*)(alog + (size_t)n*SD);
  float4 Aa = A4[0], Ab = A4[1], Ac = A4[2];
  float Av[SD] = {Aa.x,Aa.y,Aa.z,Aa.w, Ab.x,Ab.y,Ab.z,Ab.w, Ac.x,Ac.y,Ac.z,Ac.w};
  #pragma unroll
  for (int s = 0; s < SD; ++s) Av[s] = -__expf(Av[s]);
  float h[SD], apv[SD];
  #pragma unroll
  for (int s = 0; s < SD; ++s){ h[s] = 0.f; apv[s] = 1.f; }
  const size_t tok0 = (size_t)sq*TL + c*CLEN;
  for (int tt = 0; tt < CLEN; ++tt){
    const size_t tok = tok0 + tt;
    float dtv = dtb[tok*NF + n];
    float dx  = dtv * xcc[tok*NF + n];
    const float4* B4 = (const float4*)(Bmb + tok*SD);   // broadcast across lanes
    float4 Ba = B4[0], Bb = B4[1], Bc = B4[2];
    float Bv[SD] = {Ba.x,Ba.y,Ba.z,Ba.w, Bb.x,Bb.y,Bb.z,Bb.w, Bc.x,Bc.y,Bc.z,Bc.w};
    #pragma unroll
    for (int s = 0; s < SD; ++s){
      float dA = __expf(dtv*Av[s]);
      h[s] = fmaf(dA, h[s], dx*Bv[s]);
      apv[s] *= dA;
    }
  }
  const size_t base = (size_t)bid*SD*NF + n;
  #pragma unroll
  for (int s = 0; s < SD; ++s){ ap[base + s*NF] = apv[s]; hfb[base + s*NF] = h[s]; }
}

// ---- K3b: sequential combine across chunks -> initial h per chunk
__global__ __launch_bounds__(128) void k_scan_combine(
    const float* __restrict__ ap, const float* __restrict__ hfb, float* __restrict__ hinit){
  const int sq = blockIdx.x;
  const int n = threadIdx.x;
  float h[SD];
  #pragma unroll
  for (int s = 0; s < SD; ++s) h[s] = 0.f;
  for (int c = 0; c < NCH; ++c){
    const size_t base = ((size_t)sq*NCH + c)*SD*NF + n;
    #pragma unroll
    for (int s = 0; s < SD; ++s){
      hinit[base + s*NF] = h[s];
      h[s] = fmaf(ap[base + s*NF], h[s], hfb[base + s*NF]);
    }
  }
}

// ---- K3c: scan pass 2 — replay with correct h_init, emit y
__global__ __launch_bounds__(128) void k_scan_pass2(
    const float* __restrict__ dtb, const float* __restrict__ xcc,
    const float* __restrict__ Bmb, const float* __restrict__ Cmb,
    const float* __restrict__ alog, const float* __restrict__ hinit,
    float* __restrict__ yb){
  const int bid = blockIdx.x;
  const int sq = bid / NCH, c = bid - sq*NCH;
  const int n = threadIdx.x;
  const float4* A4 = (const float4*)(alog + (size_t)n*SD);
  float4 Aa = A4[0], Ab = A4[1], Ac = A4[2];
  float Av[SD] = {Aa.x,Aa.y,Aa.z,Aa.w, Ab.x,Ab.y,Ab.z,Ab.w, Ac.x,Ac.y,Ac.z,Ac.w};
  #pragma unroll
  for (int s = 0; s < SD; ++s) Av[s] = -__expf(Av[s]);
  float h[SD];
  const size_t hbase = (size_t)bid*SD*NF + n;
  #pragma unroll
  for (int s = 0; s < SD; ++s) h[s] = hinit[hbase + s*NF];
  const size_t tok0 = (size_t)sq*TL + c*CLEN;
  for (int tt = 0; tt < CLEN; ++tt){
    const size_t tok = tok0 + tt;
    float dtv = dtb[tok*NF + n];
    float dx  = dtv * xcc[tok*NF + n];
    const float4* B4 = (const float4*)(Bmb + tok*SD);
    const float4* C4 = (const float4*)(Cmb + tok*SD);
    float4 Ba=B4[0], Bb=B4[1], Bc=B4[2];
    float4 Ca=C4[0], Cb=C4[1], Cc=C4[2];
    float Bv[SD] = {Ba.x,Ba.y,Ba.z,Ba.w, Bb.x,Bb.y,Bb.z,Bb.w, Bc.x,Bc.y,Bc.z,Bc.w};
    float Cv[SD] = {Ca.x,Ca.y,Ca.z,Ca.w, Cb.x,Cb.y,Cb.z,Cb.w, Cc.x,Cc.y,Cc.z,Cc.w};
    float yv = 0.f;
    #pragma unroll
    for (int s = 0; s < SD; ++s){
      float dA = __expf(dtv*Av[s]);
      h[s] = fmaf(dA, h[s], dx*Bv[s]);
      yv = fmaf(h[s], Cv[s], yv);
    }
    yb[tok*NF + n] = yv;
  }
}

// ---- K4: y2 = (y + Dv*xc) * silu(z); seq += y2 @ out_w^T + out_b   (16 tokens/block)
__global__ __launch_bounds__(256) void k_gate_out(
    const float* __restrict__ yb, const float* __restrict__ xcc, const float* __restrict__ zb,
    const float* __restrict__ Dv, const float* __restrict__ ow, const float* __restrict__ ob,
    float* __restrict__ seq){
  __shared__ float sy[16*NF];
  const int tok0 = blockIdx.x * 16;
  for (int e = threadIdx.x; e < 16*NF; e += 256){
    int n = e & 127;
    size_t idx = (size_t)tok0*NF + e;
    float yv = fmaf(Dv[n], xcc[idx], yb[idx]);
    sy[e] = yv * siluf(zb[idx]);
  }
  __syncthreads();
  const int n = threadIdx.x & 127, jg = threadIdx.x >> 7;
  const float4* wr = (const float4*)(ow + (size_t)n*NF);
  float acc[8];
  #pragma unroll
  for (int i = 0; i < 8; ++i) acc[i] = 0.f;
  for (int k4 = 0; k4 < 32; ++k4){
    float4 w4 = wr[k4];
    #pragma unroll
    for (int i = 0; i < 8; ++i){
      float4 x4 = *((const float4*)&sy[(jg*8 + i)*NF + k4*4]);
      acc[i] = fmaf(w4.x,x4.x, fmaf(w4.y,x4.y, fmaf(w4.z,x4.z, fmaf(w4.w,x4.w, acc[i]))));
    }
  }
  const float bo = ob[n];
  #pragma unroll
  for (int i = 0; i < 8; ++i){
    size_t idx = ((size_t)(tok0 + jg*8 + i))*NF + n;
    seq[idx] += acc[i] + bo;
  }
}

// ---- K5: cross block + final LN + transpose to (B,N,T,K); one block per (b,t)
__global__ __launch_bounds__(256) void k_cross_final(
    const float* __restrict__ seq,
    const float* __restrict__ cbw, const float* __restrict__ cbb,
    const float* __restrict__ clnw, const float* __restrict__ clnb,
    const float* __restrict__ flnw, const float* __restrict__ flnb,
    float* __restrict__ out){
  const int b = blockIdx.x / TL, t = blockIdx.x % TL;
  __shared__ float Sm[30*NF];
  __shared__ float Cx[30*NF];
  __shared__ float mu[30], rsd[30];
  for (int e = threadIdx.x; e < 30*NF; e += 256){
    int k = e >> 7, n = e & 127;
    Sm[e] = seq[((size_t)(b*30 + k)*TL + t)*NF + n];
  }
  __syncthreads();
  for (int e = threadIdx.x; e < 30*NF; e += 256){
    int k = e >> 7, n = e & 127;
    const float4* wr = (const float4*)(cbw + (size_t)n*NF);
    const float4* xr = (const float4*)(&Sm[k*NF]);
    float acc2 = 0.f;
    for (int q = 0; q < 32; ++q){
      float4 w4 = wr[q], x4 = xr[q];
      acc2 = fmaf(w4.x,x4.x, fmaf(w4.y,x4.y, fmaf(w4.z,x4.z, fmaf(w4.w,x4.w, acc2))));
    }
    Cx[e] = acc2 + cbb[n];
  }
  __syncthreads();
  if (threadIdx.x < 30){
    int k = threadIdx.x;
    float s = 0.f, s2 = 0.f;
    for (int q = 0; q < NF; ++q){ float v = Cx[k*NF + q]; s += v; s2 += v*v; }
    float m = s * (1.f/128.f);
    mu[k] = m; rsd[k] = rsqrtf(s2*(1.f/128.f) - m*m + 1e-5f);
  }
  __syncthreads();
  for (int e = threadIdx.x; e < 30*NF; e += 256){
    int k = e >> 7, n = e & 127;
    float cn = (Cx[e] - mu[k])*rsd[k]*clnw[n] + clnb[n];
    float g = 0.5f*cn*(1.f + erff(cn*0.70710678118f));   // exact gelu
    Cx[e] = Sm[e] + g;
  }
  __syncthreads();
  if (threadIdx.x < 30){
    int k = threadIdx.x;
    float s = 0.f, s2 = 0.f;
    for (int q = 0; q < NF; ++q){ float v = Cx[k*NF + q]; s += v; s2 += v*v; }
    float m = s * (1.f/128.f);
    mu[k] = m; rsd[k] = rsqrtf(s2*(1.f/128.f) - m*m + 1e-5f);
  }
  __syncthreads();
  for (int e = threadIdx.x; e < 30*NF; e += 256){
    int n = e / 30, k = e - n*30;   // k fastest for coalesced write
    float v = (Cx[k*NF + n] - mu[k])*rsd[k]*flnw[n] + flnb[n];
    out[((size_t)(b*NF + n)*TL + t)*30 + k] = v;
  }
}

extern "C" void kernel_launch(void* const* d_in, const int* in_sizes, int n_in,
                              void* d_out, int out_size, void* d_ws, size_t ws_size,
                              hipStream_t stream){
  const float* x       = (const float*)d_in[0];
  const float* ln_w    = (const float*)d_in[1];
  const float* ln_b    = (const float*)d_in[2];
  const float* in_w    = (const float*)d_in[3];
  const float* in_b    = (const float*)d_in[4];
  const float* conv_w  = (const float*)d_in[5];
  const float* conv_b  = (const float*)d_in[6];
  const float* xp_w    = (const float*)d_in[7];
  const float* dtp_w   = (const float*)d_in[8];
  const float* dtp_b   = (const float*)d_in[9];
  const float* A_log   = (const float*)d_in[10];
  const float* Dv      = (const float*)d_in[11];
  const float* out_w   = (const float*)d_in[12];
  const float* out_b   = (const float*)d_in[13];
  const float* cb_w    = (const float*)d_in[14];
  const float* cb_b    = (const float*)d_in[15];
  const float* cb_ln_w = (const float*)d_in[16];
  const float* cb_ln_b = (const float*)d_in[17];
  const float* fin_ln_w= (const float*)d_in[18];
  const float* fin_ln_b= (const float*)d_in[19];
  float* out = (float*)d_out;

  const size_t SEQSZ = (size_t)BKS*TL*NF;    // 7,680,000 floats
  const size_t CHSZ  = (size_t)BKS*NF*NCH*SD; // 2,304,000 floats
  float* ws  = (float*)d_ws;
  float* seq = ws;
  float* xcr = ws + SEQSZ;        // dead after k_conv_dt -> reused for scan scratch
  float* zb  = ws + 2*SEQSZ;
  float* xcc = ws + 3*SEQSZ;
  float* dtb = ws + 4*SEQSZ;
  float* yb  = ws + 5*SEQSZ;
  float* Bmb = ws + 6*SEQSZ;
  float* Cmb = Bmb + (size_t)BKS*TL*SD;
  float* ap    = xcr;             // aliases xcr (3*CHSZ = 6.912M <= 7.68M floats)
  float* hfb   = xcr + CHSZ;
  float* hinit = xcr + 2*CHSZ;
  if (ws_size < (6*SEQSZ + 2*(size_t)BKS*TL*SD)*sizeof(float)) return; // need ~190 MB

  k_ingest<<<2*TL, 256, 0, stream>>>(x, seq);
  for (int l = 0; l < 4; ++l){
    k_ln_inproj<<<NTOK/16, 256, 0, stream>>>(seq, ln_w + l*NF, ln_b + l*NF,
        in_w + (size_t)l*2*NF*NF, in_b + l*2*NF, xcr, zb);
    k_conv_dt<<<BKS*NCH, 256, 0, stream>>>(xcr, conv_w + (size_t)l*NF*4, conv_b + l*NF,
        xp_w + (size_t)l*32*NF, dtp_w + (size_t)l*NF*RD, dtp_b + l*NF, xcc, dtb, Bmb, Cmb);
    k_scan_pass1<<<BKS*NCH, NF, 0, stream>>>(dtb, xcc, Bmb, A_log + (size_t)l*NF*SD, ap, hfb);
    k_scan_combine<<<BKS, NF, 0, stream>>>(ap, hfb, hinit);
    k_scan_pass2<<<BKS*NCH, NF, 0, stream>>>(dtb, xcc, Bmb, Cmb, A_log + (size_t)l*NF*SD, hinit, yb);
    k_gate_out<<<NTOK/16, 256, 0, stream>>>(yb, xcc, zb, Dv + l*NF,
        out_w + (size_t)l*NF*NF, out_b + l*NF, seq);
  }
  k_cross_final<<<2*TL, 256, 0, stream>>>(seq, cb_w, cb_b, cb_ln_w, cb_ln_b, fin_ln_w, fin_ln_b, out);
}